// Round 1
// baseline (1000.688 us; speedup 1.0000x reference)
//
#include <hip/hip_runtime.h>
#include <stdint.h>

#define SQ   2048
#define DIN  4096
#define NH   32
#define NKV  8
#define HD   128
#define NQKV 6144

typedef float f32x4 __attribute__((ext_vector_type(4)));
typedef short bf16x8 __attribute__((ext_vector_type(8)));

__device__ __forceinline__ short f2bf(float f) {
  union { float f; uint32_t u; } v; v.f = f;
  uint32_t r = (v.u + 0x7FFFu + ((v.u >> 16) & 1u)) >> 16;
  return (short)r;
}

// ---------------- fp32 -> bf16 elementwise convert ----------------
__global__ void cvt_bf16(const float* __restrict__ src, short* __restrict__ dst, long n) {
  long i = ((long)blockIdx.x * blockDim.x + threadIdx.x) * 4;
  if (i + 3 < n) {
    float4 v = *(const float4*)(src + i);
    short o[4] = { f2bf(v.x), f2bf(v.y), f2bf(v.z), f2bf(v.w) };
    *(uint2*)(dst + i) = *(uint2*)o;
  }
}

// ---------------- tiled transpose + convert: dst[c][r] = src[r][c] ----------------
// src fp32 (rows x cols, ld = ldS), dst bf16 (cols x rows, ld = ldD), z adds strides.
__global__ __launch_bounds__(256) void transpose_cvt(const float* __restrict__ src, int ldS, long zS,
                                                     short* __restrict__ dst, int ldD, long zD) {
  __shared__ float tile[64][65];
  src += (long)blockIdx.z * zS;
  dst += (long)blockIdx.z * zD;
  int r0 = blockIdx.y * 64, c0 = blockIdx.x * 64;
  int tid = threadIdx.x;
#pragma unroll
  for (int i = 0; i < 16; ++i) {
    int idx = i * 256 + tid;
    int rr = idx >> 6, cc = idx & 63;
    tile[rr][cc] = src[(long)(r0 + rr) * ldS + c0 + cc];
  }
  __syncthreads();
#pragma unroll
  for (int i = 0; i < 16; ++i) {
    int idx = i * 256 + tid;
    int dr = idx >> 6, dc = idx & 63;       // dst row = c0+dr, dst col = r0+dc
    dst[(long)(c0 + dr) * ldD + r0 + dc] = f2bf(tile[dc][dr]);
  }
}

// ---------------- bf16 MFMA GEMM: C(MxN) = A(MxK) * Bt(NxK)^T, fp32 out ----------------
#define BM 128
#define BN 128
#define BK 32
__global__ __launch_bounds__(256) void gemm_bf16(const short* __restrict__ A, const short* __restrict__ Bt,
                                                 float* __restrict__ C, int M, int N, int K) {
  __shared__ __align__(16) short As[BM * BK];
  __shared__ __align__(16) short Bs[BN * BK];
  int tid = threadIdx.x;
  int wave = tid >> 6, lane = tid & 63;
  int l16 = lane & 15, lq = lane >> 4;
  int m0 = blockIdx.y * BM, n0 = blockIdx.x * BN;
  int wm = (wave >> 1) * 64, wn = (wave & 1) * 64;
  f32x4 acc[4][4] = {};
  for (int k0 = 0; k0 < K; k0 += BK) {
#pragma unroll
    for (int h = 0; h < 2; ++h) {
      int c = tid + h * 256;
      int row = c >> 2, kc = (c & 3) * 8;
      *(uint4*)&As[c * 8] = *(const uint4*)&A[(long)(m0 + row) * K + k0 + kc];
      *(uint4*)&Bs[c * 8] = *(const uint4*)&Bt[(long)(n0 + row) * K + k0 + kc];
    }
    __syncthreads();
    bf16x8 af[4], bfr[4];
#pragma unroll
    for (int i = 0; i < 4; ++i) af[i]  = *(const bf16x8*)&As[(wm + i * 16 + l16) * BK + lq * 8];
#pragma unroll
    for (int j = 0; j < 4; ++j) bfr[j] = *(const bf16x8*)&Bs[(wn + j * 16 + l16) * BK + lq * 8];
#pragma unroll
    for (int i = 0; i < 4; ++i)
#pragma unroll
      for (int j = 0; j < 4; ++j)
        acc[i][j] = __builtin_amdgcn_mfma_f32_16x16x32_bf16(af[i], bfr[j], acc[i][j], 0, 0, 0);
    __syncthreads();
  }
#pragma unroll
  for (int i = 0; i < 4; ++i)
#pragma unroll
    for (int j = 0; j < 4; ++j)
#pragma unroll
      for (int r = 0; r < 4; ++r) {
        int row = m0 + wm + i * 16 + lq * 4 + r;
        int col = n0 + wn + j * 16 + l16;
        C[(long)row * N + col] = acc[i][j][r];
      }
}

// ---------------- fused LayerNorm + RoPE, fp32 qkv -> bf16 q_rope / k_rope ----------------
// grid (SQ, 40): slice<32 -> q head; 32..39 -> k group. block = 64 (1 wave), thread t owns d=t and d=t+64.
__global__ __launch_bounds__(64) void ln_rope(const float* __restrict__ qkv,
                                              const float* __restrict__ cosb, const float* __restrict__ sinb,
                                              const float* __restrict__ qw, const float* __restrict__ qb,
                                              const float* __restrict__ kw, const float* __restrict__ kb,
                                              short* __restrict__ qo, short* __restrict__ ko) {
  int s = blockIdx.x, slice = blockIdx.y, t = threadIdx.x;
  bool isq = slice < NH;
  int off = isq ? slice * HD : DIN + (slice - NH) * HD;
  const float* src = qkv + (long)s * NQKV + off;
  float v0 = src[t], v1 = src[t + 64];
  float sum = v0 + v1, ss = v0 * v0 + v1 * v1;
#pragma unroll
  for (int o = 1; o < 64; o <<= 1) { sum += __shfl_xor(sum, o); ss += __shfl_xor(ss, o); }
  float mu = sum * (1.f / 128.f);
  float var = ss * (1.f / 128.f) - mu * mu;
  float rstd = rsqrtf(var + 1e-6f);
  const float* w  = isq ? qw : kw;
  const float* bb = isq ? qb : kb;
  float n0 = (v0 - mu) * rstd * w[t]      + bb[t];
  float n1 = (v1 - mu) * rstd * w[t + 64] + bb[t + 64];
  float c0 = cosb[s * HD + t], c1 = cosb[s * HD + t + 64];
  float s0 = sinb[s * HD + t], s1 = sinb[s * HD + t + 64];
  float o0 = n0 * c0 - n1 * s0;   // rot[d]   = -x[d+64]
  float o1 = n1 * c1 + n0 * s1;   // rot[d+64] = x[d]
  short* dst = isq ? (qo + ((long)slice * SQ + s) * HD)
                   : (ko + ((long)(slice - NH) * SQ + s) * HD);
  dst[t] = f2bf(o0);
  dst[t + 64] = f2bf(o1);
}

// ---------------- flash attention, bf16 MFMA ----------------
// grid (32 qtiles, 32 heads), block 256 = 4 waves; wave w owns q rows qt*64 + w*16 .. +15.
// q  : (NH, SQ, HD) bf16     k : (NKV, SQ, HD) bf16    vT : (NKV, HD, SQ) bf16
// ctx: (SQ, NH*HD) bf16
__global__ __launch_bounds__(256) void attn(const short* __restrict__ q, const short* __restrict__ k,
                                            const short* __restrict__ vT, short* __restrict__ ctx) {
  int qt = blockIdx.x, h = blockIdx.y, g = h >> 2;
  int tid = threadIdx.x, w = tid >> 6, lane = tid & 63;
  int l16 = lane & 15, lq = lane >> 4;
  int qbase = qt * 64 + w * 16;
  __shared__ __align__(16) short pbuf[4][16 * 72];   // row stride 72 shorts: conflict-free b128
  const short* qh = q + (long)h * SQ * HD;
  const short* kg = k + (long)g * SQ * HD;
  const short* vg = vT + (long)g * HD * SQ;
  bf16x8 aq[4];
#pragma unroll
  for (int kk = 0; kk < 4; ++kk)
    aq[kk] = *(const bf16x8*)&qh[(long)(qbase + l16) * HD + kk * 32 + lq * 8];
  float m_r[4], l_r[4];
  f32x4 acc[8] = {};
#pragma unroll
  for (int r = 0; r < 4; ++r) { m_r[r] = -__builtin_inff(); l_r[r] = 0.f; }
  const float sc = 0.08838834764831845f * 1.4426950408889634f;  // 1/sqrt(128) * log2(e)
  for (int kt = 0; kt <= qt; ++kt) {
    f32x4 s4[4];
#pragma unroll
    for (int b = 0; b < 4; ++b) { s4[b] = (f32x4){0.f, 0.f, 0.f, 0.f}; }
#pragma unroll
    for (int b = 0; b < 4; ++b)
#pragma unroll
      for (int kk = 0; kk < 4; ++kk) {
        bf16x8 bk = *(const bf16x8*)&kg[(long)(kt * 64 + b * 16 + l16) * HD + kk * 32 + lq * 8];
        s4[b] = __builtin_amdgcn_mfma_f32_16x16x32_bf16(aq[kk], bk, s4[b], 0, 0, 0);
      }
    // scale + causal mask (key > qrow -> -inf)
    int qrow0 = qbase + lq * 4;
#pragma unroll
    for (int b = 0; b < 4; ++b) {
      int key = kt * 64 + b * 16 + l16;
#pragma unroll
      for (int r = 0; r < 4; ++r) {
        float val = s4[b][r] * sc;
        s4[b][r] = (key > qrow0 + r) ? -__builtin_inff() : val;
      }
    }
    float p[4][4];
#pragma unroll
    for (int r = 0; r < 4; ++r) {
      float mx = fmaxf(fmaxf(s4[0][r], s4[1][r]), fmaxf(s4[2][r], s4[3][r]));
#pragma unroll
      for (int o = 1; o < 16; o <<= 1) mx = fmaxf(mx, __shfl_xor(mx, o));
      float mnew = fmaxf(m_r[r], mx);
      float alpha = exp2f(m_r[r] - mnew);
      float sum = 0.f;
#pragma unroll
      for (int b = 0; b < 4; ++b) { float pv = exp2f(s4[b][r] - mnew); p[b][r] = pv; sum += pv; }
#pragma unroll
      for (int o = 1; o < 16; o <<= 1) sum += __shfl_xor(sum, o);
      l_r[r] = l_r[r] * alpha + sum;
      m_r[r] = mnew;
#pragma unroll
      for (int n = 0; n < 8; ++n) acc[n][r] *= alpha;
    }
    // P (C-layout) -> LDS -> A-layout fragments
#pragma unroll
    for (int b = 0; b < 4; ++b)
#pragma unroll
      for (int r = 0; r < 4; ++r)
        pbuf[w][(lq * 4 + r) * 72 + b * 16 + l16] = f2bf(p[b][r]);
#pragma unroll
    for (int kk = 0; kk < 2; ++kk) {
      bf16x8 pf = *(const bf16x8*)&pbuf[w][l16 * 72 + kk * 32 + lq * 8];
#pragma unroll
      for (int n = 0; n < 8; ++n) {
        bf16x8 vf = *(const bf16x8*)&vg[(long)(n * 16 + l16) * SQ + kt * 64 + kk * 32 + lq * 8];
        acc[n] = __builtin_amdgcn_mfma_f32_16x16x32_bf16(pf, vf, acc[n], 0, 0, 0);
      }
    }
  }
#pragma unroll
  for (int n = 0; n < 8; ++n)
#pragma unroll
    for (int r = 0; r < 4; ++r) {
      int srow = qbase + lq * 4 + r;
      ctx[(long)srow * (NH * HD) + h * HD + n * 16 + l16] = f2bf(acc[n][r] / l_r[r]);
    }
}

// ---------------- workspace layout (aliased by liveness) ----------------
// XB      [0,        16.7MB)   bf16 x          -- dead after GEMM1
// Q_ROPE  [0,        16.7MB)   (aliases XB)
// WQKVT   [16.7MB,   67.1MB)   -- dead after GEMM1
//   K_ROPE [16.7MB, 21.0MB), VT [21.0MB, 25.2MB), CTX [25.2MB, 41.9MB) (alias WQKVT)
// WOT     [67.1MB,  100.7MB)
// QKV     [100.7MB, 151.0MB)   fp32
#define XB_OFF     0L
#define QR_OFF     0L
#define WQKVT_OFF  16777216L
#define KR_OFF     16777216L
#define VT_OFF     20971520L
#define CTX_OFF    25165824L
#define WOT_OFF    67108864L
#define QKV_OFF    100663296L

extern "C" void kernel_launch(void* const* d_in, const int* in_sizes, int n_in,
                              void* d_out, int out_size, void* d_ws, size_t ws_size,
                              hipStream_t stream) {
  const float* x    = (const float*)d_in[0];
  const float* cosb = (const float*)d_in[2];
  const float* sinb = (const float*)d_in[3];
  const float* Wq   = (const float*)d_in[4];
  const float* Wk   = (const float*)d_in[5];
  const float* Wv   = (const float*)d_in[6];
  const float* Wo   = (const float*)d_in[7];
  const float* qnw  = (const float*)d_in[8];
  const float* qnb  = (const float*)d_in[9];
  const float* knw  = (const float*)d_in[10];
  const float* knb  = (const float*)d_in[11];

  char* ws = (char*)d_ws;
  short* xb    = (short*)(ws + XB_OFF);
  short* qr    = (short*)(ws + QR_OFF);
  short* wqkvt = (short*)(ws + WQKVT_OFF);
  short* kr    = (short*)(ws + KR_OFF);
  short* vt    = (short*)(ws + VT_OFF);
  short* ctx   = (short*)(ws + CTX_OFF);
  short* wot   = (short*)(ws + WOT_OFF);
  float* qkv   = (float*)(ws + QKV_OFF);

  // 1. x -> bf16
  cvt_bf16<<<8192, 256, 0, stream>>>(x, xb, (long)SQ * DIN);
  // 2. weights -> bf16, transposed to (N, K)
  transpose_cvt<<<dim3(64, 64, 1), 256, 0, stream>>>(Wq, 4096, 0L, wqkvt, 4096, 0L);
  transpose_cvt<<<dim3(16, 64, 1), 256, 0, stream>>>(Wk, 1024, 0L, wqkvt + (long)4096 * 4096, 4096, 0L);
  transpose_cvt<<<dim3(16, 64, 1), 256, 0, stream>>>(Wv, 1024, 0L, wqkvt + (long)5120 * 4096, 4096, 0L);
  transpose_cvt<<<dim3(64, 64, 1), 256, 0, stream>>>(Wo, 4096, 0L, wot, 4096, 0L);
  // 3. fused QKV projection: (2048 x 4096) x (6144 x 4096)^T -> fp32 (2048 x 6144)
  gemm_bf16<<<dim3(NQKV / BN, SQ / BM), 256, 0, stream>>>(xb, wqkvt, qkv, SQ, NQKV, DIN);
  // 4. LN + RoPE -> bf16 q (h,s,d), k (g,s,d)
  ln_rope<<<dim3(SQ, NH + NKV), 64, 0, stream>>>(qkv, cosb, sinb, qnw, qnb, knw, knb, qr, kr);
  // 5. V: transpose-convert qkv slice -> vT (g, d, s) bf16
  transpose_cvt<<<dim3(2, 32, 8), 256, 0, stream>>>(qkv + 5120, NQKV, 128L, vt, SQ, (long)HD * SQ);
  // 6. flash attention -> ctx bf16 (s, h*128+d)
  attn<<<dim3(SQ / 64, NH), 256, 0, stream>>>(qr, kr, vt, ctx);
  // 7. out projection: (2048 x 4096) x (4096 x 4096)^T -> fp32 d_out
  gemm_bf16<<<dim3(DIN / BN, SQ / BM), 256, 0, stream>>>(ctx, wot, (float*)d_out, SQ, DIN, DIN);
}

// Round 2
// 609.854 us; speedup vs baseline: 1.6409x; 1.6409x over previous
//
#include <hip/hip_runtime.h>
#include <stdint.h>

#define SQ   2048
#define DIN  4096
#define NH   32
#define NKV  8
#define HD   128
#define NQKV 6144

typedef float f32x4 __attribute__((ext_vector_type(4)));
typedef short bf16x8 __attribute__((ext_vector_type(8)));

__device__ __forceinline__ short f2bf(float f) {
  union { float f; uint32_t u; } v; v.f = f;
  uint32_t r = (v.u + 0x7FFFu + ((v.u >> 16) & 1u)) >> 16;
  return (short)r;
}

// async global -> LDS, 16 bytes per lane, dst = lds_base + lane*16 (HW-fixed)
__device__ __forceinline__ void gl2lds(const void* g, void* l) {
  __builtin_amdgcn_global_load_lds(
      (const __attribute__((address_space(1))) void*)g,
      (__attribute__((address_space(3))) void*)l, 16, 0, 0);
}

// ---------------- fp32 -> bf16 elementwise convert ----------------
__global__ void cvt_bf16(const float* __restrict__ src, short* __restrict__ dst, long n) {
  long i = ((long)blockIdx.x * blockDim.x + threadIdx.x) * 4;
  if (i + 3 < n) {
    float4 v = *(const float4*)(src + i);
    short o[4] = { f2bf(v.x), f2bf(v.y), f2bf(v.z), f2bf(v.w) };
    *(uint2*)(dst + i) = *(uint2*)o;
  }
}

// ---------------- tiled transpose + convert: dst[c][r] = src[r][c] ----------------
__global__ __launch_bounds__(256) void transpose_cvt(const float* __restrict__ src, int ldS, long zS,
                                                     short* __restrict__ dst, int ldD, long zD) {
  __shared__ float tile[64][65];
  src += (long)blockIdx.z * zS;
  dst += (long)blockIdx.z * zD;
  int r0 = blockIdx.y * 64, c0 = blockIdx.x * 64;
  int tid = threadIdx.x;
#pragma unroll
  for (int i = 0; i < 16; ++i) {
    int idx = i * 256 + tid;
    int rr = idx >> 6, cc = idx & 63;
    tile[rr][cc] = src[(long)(r0 + rr) * ldS + c0 + cc];
  }
  __syncthreads();
#pragma unroll
  for (int i = 0; i < 16; ++i) {
    int idx = i * 256 + tid;
    int dr = idx >> 6, dc = idx & 63;
    dst[(long)(c0 + dr) * ldD + r0 + dc] = f2bf(tile[dc][dr]);
  }
}

// ---------------- bf16 MFMA GEMM (m97 structure): C = A(MxK) * Bt(NxK)^T ----------------
// LDS layout: row-major [row][BK], 16B chunks swizzled: slot = chunk ^ ((row>>1)&3).
#define BM 128
#define BN 128
#define BK 32
__global__ __launch_bounds__(256) void gemm_bf16(const short* __restrict__ A, const short* __restrict__ Bt,
                                                 float* __restrict__ C, int M, int N, int K) {
  __shared__ __align__(16) short As[BM * BK];
  __shared__ __align__(16) short Bs[BN * BK];
  int tid = threadIdx.x;
  int wave = tid >> 6, lane = tid & 63;
  int l16 = lane & 15, lq = lane >> 4;
  int m0 = blockIdx.y * BM, n0 = blockIdx.x * BN;
  int wm = (wave >> 1) * 64, wn = (wave & 1) * 64;
  // staging address precompute: this wave's 2 calls cover rows call*16 + lane/4
  int ch = (lane & 3) ^ ((lane >> 3) & 3);   // swizzled global chunk this lane fetches
  f32x4 acc[4][4] = {};
  for (int k0 = 0; k0 < K; k0 += BK) {
#pragma unroll
    for (int c = 0; c < 2; ++c) {
      int call = wave * 2 + c;
      int r = call * 16 + (lane >> 2);
      gl2lds(&A[(long)(m0 + r) * K + k0 + ch * 8], &As[call * 512]);
      gl2lds(&Bt[(long)(n0 + r) * K + k0 + ch * 8], &Bs[call * 512]);
    }
    __syncthreads();
    bf16x8 af[4], bfr[4];
#pragma unroll
    for (int i = 0; i < 4; ++i) {
      int row = wm + i * 16 + l16;
      af[i] = *(const bf16x8*)&As[row * BK + (lq ^ ((row >> 1) & 3)) * 8];
    }
#pragma unroll
    for (int j = 0; j < 4; ++j) {
      int row = wn + j * 16 + l16;
      bfr[j] = *(const bf16x8*)&Bs[row * BK + (lq ^ ((row >> 1) & 3)) * 8];
    }
#pragma unroll
    for (int i = 0; i < 4; ++i)
#pragma unroll
      for (int j = 0; j < 4; ++j)
        acc[i][j] = __builtin_amdgcn_mfma_f32_16x16x32_bf16(af[i], bfr[j], acc[i][j], 0, 0, 0);
    __syncthreads();
  }
#pragma unroll
  for (int i = 0; i < 4; ++i)
#pragma unroll
    for (int j = 0; j < 4; ++j)
#pragma unroll
      for (int r = 0; r < 4; ++r) {
        int row = m0 + wm + i * 16 + lq * 4 + r;
        int col = n0 + wn + j * 16 + l16;
        C[(long)row * N + col] = acc[i][j][r];
      }
}

// ---------------- fused LayerNorm + RoPE ----------------
__global__ __launch_bounds__(64) void ln_rope(const float* __restrict__ qkv,
                                              const float* __restrict__ cosb, const float* __restrict__ sinb,
                                              const float* __restrict__ qw, const float* __restrict__ qb,
                                              const float* __restrict__ kw, const float* __restrict__ kb,
                                              short* __restrict__ qo, short* __restrict__ ko) {
  int s = blockIdx.x, slice = blockIdx.y, t = threadIdx.x;
  bool isq = slice < NH;
  int off = isq ? slice * HD : DIN + (slice - NH) * HD;
  const float* src = qkv + (long)s * NQKV + off;
  float v0 = src[t], v1 = src[t + 64];
  float sum = v0 + v1, ss = v0 * v0 + v1 * v1;
#pragma unroll
  for (int o = 1; o < 64; o <<= 1) { sum += __shfl_xor(sum, o); ss += __shfl_xor(ss, o); }
  float mu = sum * (1.f / 128.f);
  float var = ss * (1.f / 128.f) - mu * mu;
  float rstd = rsqrtf(var + 1e-6f);
  const float* w  = isq ? qw : kw;
  const float* bb = isq ? qb : kb;
  float n0 = (v0 - mu) * rstd * w[t]      + bb[t];
  float n1 = (v1 - mu) * rstd * w[t + 64] + bb[t + 64];
  float c0 = cosb[s * HD + t], c1 = cosb[s * HD + t + 64];
  float s0 = sinb[s * HD + t], s1 = sinb[s * HD + t + 64];
  float o0 = n0 * c0 - n1 * s0;
  float o1 = n1 * c1 + n0 * s1;
  short* dst = isq ? (qo + ((long)slice * SQ + s) * HD)
                   : (ko + ((long)(slice - NH) * SQ + s) * HD);
  dst[t] = f2bf(o0);
  dst[t + 64] = f2bf(o1);
}

// ---------------- flash attention, LDS-staged K/V, causal-paired ----------------
// grid (16 pairs, 32 heads), block 256 = 4 waves. Block p handles q-tiles p and 31-p
// (33 key-tiles each -> perfectly balanced). K tile 64x128 and V^T tile 128x64 staged
// in LDS via global_load_lds with XOR-chunk swizzle (conflict-free b128 frag reads).
__global__ __launch_bounds__(256) void attn(const short* __restrict__ q, const short* __restrict__ k,
                                            const short* __restrict__ vT, short* __restrict__ ctx) {
  int pair = blockIdx.x, h = blockIdx.y, g = h >> 2;
  int tid = threadIdx.x, w = tid >> 6, lane = tid & 63;
  int l16 = lane & 15, lq = lane >> 4;
  __shared__ __align__(16) short Ks[64 * 128];    // 16 KB: [key][128], chunk16 ^ (key&15)
  __shared__ __align__(16) short Vs[128 * 64];    // 16 KB: [d][64],   chunk8  ^ (d&7)
  __shared__ __align__(16) short pbuf[4][16 * 72];
  const short* qh = q + (long)h * SQ * HD;
  const short* kg = k + (long)g * SQ * HD;
  const short* vg = vT + (long)g * HD * SQ;
  // staging lane constants
  int kr = (w * 4) * 4 + (lane >> 4);             // K: call w*4+j covers rows (w*4+j)*4 + lane/16
  int vrw = (w * 4) * 8 + (lane >> 3);            // V: call w*4+j covers rows (w*4+j)*8 + lane/8
  const float sc = 0.08838834764831845f * 1.4426950408889634f;  // 1/sqrt(128) * log2(e)

  for (int st = 0; st < 2; ++st) {
    int qt = st ? (31 - pair) : pair;
    int qbase = qt * 64 + w * 16;
    bf16x8 aq[4];
#pragma unroll
    for (int kk = 0; kk < 4; ++kk)
      aq[kk] = *(const bf16x8*)&qh[(long)(qbase + l16) * HD + kk * 32 + lq * 8];
    float m_r[4], l_r[4];
    f32x4 acc[8] = {};
#pragma unroll
    for (int r = 0; r < 4; ++r) { m_r[r] = -__builtin_inff(); l_r[r] = 0.f; }

    for (int kt = 0; kt <= qt; ++kt) {
      // ---- stage K (16 calls) + V (16 calls); this wave does 4 of each ----
#pragma unroll
      for (int j = 0; j < 4; ++j) {
        int call = w * 4 + j;
        int r = kr + j * 4;                        // key row in tile
        int chk = (lane & 15) ^ (r & 15);
        gl2lds(&kg[(long)(kt * 64 + r) * HD + chk * 8], &Ks[call * 512]);
        int rv = vrw + j * 8;                      // d row in tile
        int chv = (lane & 7) ^ (rv & 7);
        gl2lds(&vg[(long)rv * SQ + kt * 64 + chv * 8], &Vs[call * 512]);
      }
      __syncthreads();
      // ---- QK^T from LDS ----
      f32x4 s4[4];
#pragma unroll
      for (int b = 0; b < 4; ++b) s4[b] = (f32x4){0.f, 0.f, 0.f, 0.f};
#pragma unroll
      for (int b = 0; b < 4; ++b) {
        int krow = b * 16 + l16;
#pragma unroll
        for (int kk = 0; kk < 4; ++kk) {
          bf16x8 bk = *(const bf16x8*)&Ks[krow * 128 + ((kk * 4 + lq) ^ (krow & 15)) * 8];
          s4[b] = __builtin_amdgcn_mfma_f32_16x16x32_bf16(aq[kk], bk, s4[b], 0, 0, 0);
        }
      }
      // ---- scale + causal mask ----
      int qrow0 = qbase + lq * 4;
#pragma unroll
      for (int b = 0; b < 4; ++b) {
        int key = kt * 64 + b * 16 + l16;
#pragma unroll
        for (int r = 0; r < 4; ++r) {
          float val = s4[b][r] * sc;
          s4[b][r] = (key > qrow0 + r) ? -__builtin_inff() : val;
        }
      }
      // ---- online softmax ----
      float p[4][4];
#pragma unroll
      for (int r = 0; r < 4; ++r) {
        float mx = fmaxf(fmaxf(s4[0][r], s4[1][r]), fmaxf(s4[2][r], s4[3][r]));
#pragma unroll
        for (int o = 1; o < 16; o <<= 1) mx = fmaxf(mx, __shfl_xor(mx, o));
        float mnew = fmaxf(m_r[r], mx);
        float alpha = exp2f(m_r[r] - mnew);
        float sum = 0.f;
#pragma unroll
        for (int b = 0; b < 4; ++b) { float pv = exp2f(s4[b][r] - mnew); p[b][r] = pv; sum += pv; }
#pragma unroll
        for (int o = 1; o < 16; o <<= 1) sum += __shfl_xor(sum, o);
        l_r[r] = l_r[r] * alpha + sum;
        m_r[r] = mnew;
#pragma unroll
        for (int n = 0; n < 8; ++n) acc[n][r] *= alpha;
      }
      // ---- P (C-layout) -> LDS -> A-layout ----
#pragma unroll
      for (int b = 0; b < 4; ++b)
#pragma unroll
        for (int r = 0; r < 4; ++r)
          pbuf[w][(lq * 4 + r) * 72 + b * 16 + l16] = f2bf(p[b][r]);
      // ---- PV from LDS ----
#pragma unroll
      for (int kk = 0; kk < 2; ++kk) {
        bf16x8 pf = *(const bf16x8*)&pbuf[w][l16 * 72 + kk * 32 + lq * 8];
#pragma unroll
        for (int n = 0; n < 8; ++n) {
          int vrow = n * 16 + l16;
          bf16x8 vf = *(const bf16x8*)&Vs[vrow * 64 + ((kk * 4 + lq) ^ (vrow & 7)) * 8];
          acc[n] = __builtin_amdgcn_mfma_f32_16x16x32_bf16(pf, vf, acc[n], 0, 0, 0);
        }
      }
      __syncthreads();
    }
    // ---- epilogue ----
#pragma unroll
    for (int n = 0; n < 8; ++n)
#pragma unroll
      for (int r = 0; r < 4; ++r) {
        int srow = qbase + lq * 4 + r;
        ctx[(long)srow * (NH * HD) + h * HD + n * 16 + l16] = f2bf(acc[n][r] / l_r[r]);
      }
  }
}

// ---------------- workspace layout ----------------
#define XB_OFF     0L
#define QR_OFF     0L
#define WQKVT_OFF  16777216L
#define KR_OFF     16777216L
#define VT_OFF     20971520L
#define CTX_OFF    25165824L
#define WOT_OFF    67108864L
#define QKV_OFF    100663296L

extern "C" void kernel_launch(void* const* d_in, const int* in_sizes, int n_in,
                              void* d_out, int out_size, void* d_ws, size_t ws_size,
                              hipStream_t stream) {
  const float* x    = (const float*)d_in[0];
  const float* cosb = (const float*)d_in[2];
  const float* sinb = (const float*)d_in[3];
  const float* Wq   = (const float*)d_in[4];
  const float* Wk   = (const float*)d_in[5];
  const float* Wv   = (const float*)d_in[6];
  const float* Wo   = (const float*)d_in[7];
  const float* qnw  = (const float*)d_in[8];
  const float* qnb  = (const float*)d_in[9];
  const float* knw  = (const float*)d_in[10];
  const float* knb  = (const float*)d_in[11];

  char* ws = (char*)d_ws;
  short* xb    = (short*)(ws + XB_OFF);
  short* qr    = (short*)(ws + QR_OFF);
  short* wqkvt = (short*)(ws + WQKVT_OFF);
  short* krp   = (short*)(ws + KR_OFF);
  short* vt    = (short*)(ws + VT_OFF);
  short* ctx   = (short*)(ws + CTX_OFF);
  short* wot   = (short*)(ws + WOT_OFF);
  float* qkv   = (float*)(ws + QKV_OFF);

  cvt_bf16<<<8192, 256, 0, stream>>>(x, xb, (long)SQ * DIN);
  transpose_cvt<<<dim3(64, 64, 1), 256, 0, stream>>>(Wq, 4096, 0L, wqkvt, 4096, 0L);
  transpose_cvt<<<dim3(16, 64, 1), 256, 0, stream>>>(Wk, 1024, 0L, wqkvt + (long)4096 * 4096, 4096, 0L);
  transpose_cvt<<<dim3(16, 64, 1), 256, 0, stream>>>(Wv, 1024, 0L, wqkvt + (long)5120 * 4096, 4096, 0L);
  transpose_cvt<<<dim3(64, 64, 1), 256, 0, stream>>>(Wo, 4096, 0L, wot, 4096, 0L);
  gemm_bf16<<<dim3(NQKV / BN, SQ / BM), 256, 0, stream>>>(xb, wqkvt, qkv, SQ, NQKV, DIN);
  ln_rope<<<dim3(SQ, NH + NKV), 64, 0, stream>>>(qkv, cosb, sinb, qnw, qnb, knw, knb, qr, krp);
  transpose_cvt<<<dim3(2, 32, 8), 256, 0, stream>>>(qkv + 5120, NQKV, 128L, vt, SQ, (long)HD * SQ);
  attn<<<dim3(16, NH), 256, 0, stream>>>(qr, krp, vt, ctx);
  gemm_bf16<<<dim3(DIN / BN, SQ / BM), 256, 0, stream>>>(ctx, wot, (float*)d_out, SQ, DIN, DIN);
}